// Round 11
// baseline (175.176 us; speedup 1.0000x reference)
//
#include <hip/hip_runtime.h>
#include <cstdint>

// Head attention: x[4,4096,1024] fp32, Wq/Wk/Wv[1024,64] fp32 -> out[4,4096,64] fp32.
// Round 11 = round 10 with the slot-stride bug fixed (second x-DMA granule goes to
// xl+4096 (slot interior), not xl+8192 (next slot) — r10's absmax=6.0).
//  K0: wt_prep  - coalesced W transpose -> bf16 wt[which][n][k], stride 1088
//  K1: qkv_proj - 16-row blocks, x-dbuf DMA + JIT W loads, 12 MFMA/wave/step
//  K2: flash    - item (b, qt64, h4): 64 q-rows, KV dbuf, additive partials
//  K3: combine  - out = sum_h O_h / sum_h l_h

typedef __bf16 bf16;
typedef __bf16 bf16x8 __attribute__((ext_vector_type(8)));
typedef __bf16 bf16x4 __attribute__((ext_vector_type(4)));
typedef float  f32x4  __attribute__((ext_vector_type(4)));

#define MFMA16(a, b, c) __builtin_amdgcn_mfma_f32_16x16x32_bf16((a), (b), (c), 0, 0, 0)

#if __has_builtin(__builtin_amdgcn_exp2f)
#define EXP2(x) __builtin_amdgcn_exp2f(x)
#else
#define EXP2(x) exp2f(x)
#endif

#define B_SZ 4
#define T_SZ 4096
#define C_SZ 1024
#define H_SZ 64
#define M_SZ (B_SZ * T_SZ)
#define QSCALE (1.4426950408889634f / 32.0f)   // log2(e)/sqrt(1024)
#define P_STR 4160                             // floats per partial: 64x64 O + 64 l
#define WT_STR 1088
#define WT_SZ  (H_SZ * WT_STR)

// async 16B global->LDS DMA; LDS dest is wave-uniform base + lane*16.
__device__ __forceinline__ void dma16(const void* g, void* l) {
    __builtin_amdgcn_global_load_lds(
        (const __attribute__((address_space(1))) uint32_t*)(uintptr_t)g,
        (__attribute__((address_space(3))) uint32_t*)(uint32_t)(uintptr_t)l,
        16, 0, 0);
}

// -------------------------------------------------------------------------
// K0: coalesced transpose W[k][n] -> wt[which][n][k] bf16, stride 1088.
// grid 48 x 256; block = one 64-k slice of one W. Wq pre-scaled.
// -------------------------------------------------------------------------
__global__ __launch_bounds__(256) void wt_prep(
    const float* __restrict__ Wq, const float* __restrict__ Wk,
    const float* __restrict__ Wv, bf16* __restrict__ wt)
{
    const int which = blockIdx.x >> 4, kt = blockIdx.x & 15;
    const float* W = (which == 0) ? Wq : ((which == 1) ? Wk : Wv);
    const float s = (which == 0) ? QSCALE : 1.0f;
    const int t = threadIdx.x;

    __shared__ bf16 tile[64][72];

    #pragma unroll
    for (int j = 0; j < 4; ++j) {
        const int f4 = t + j * 256;
        const int kl = f4 >> 4, n4 = f4 & 15;
        const float4 v = *(const float4*)(W + (size_t)(kt * 64 + kl) * H_SZ + n4 * 4);
        tile[n4 * 4 + 0][kl] = (bf16)(v.x * s);
        tile[n4 * 4 + 1][kl] = (bf16)(v.y * s);
        tile[n4 * 4 + 2][kl] = (bf16)(v.z * s);
        tile[n4 * 4 + 3][kl] = (bf16)(v.w * s);
    }
    __syncthreads();
    const int n = t >> 2, kk = (t & 3) * 16;
    bf16* dst = wt + (size_t)which * WT_SZ + (size_t)n * WT_STR + kt * 64 + kk;
    *(bf16x8*)dst       = *(const bf16x8*)&tile[n][kk];
    *(bf16x8*)(dst + 8) = *(const bf16x8*)&tile[n][kk + 8];
}

// -------------------------------------------------------------------------
// K1: qkv. grid 1024 x 256 (4 waves). Block = 16 rows x 192 fused cols.
// 8 steps of BK=128. x: DMA dbuf slots, layout [ss4][quad][row16][8f]
// (8KB/slot; per-thread granules at +0 and +4096 WITHIN the slot).
// W: JIT bf16x8 VGPR loads from wt (L1/L2-hot). 12 MFMA/wave/step.
// -------------------------------------------------------------------------
__global__ __launch_bounds__(256) void qkv_proj(
    const float* __restrict__ x, const bf16* __restrict__ wt,
    bf16* __restrict__ qw, bf16* __restrict__ kw2, bf16* __restrict__ vtw2)
{
    const int m0 = blockIdx.x * 16;
    const int tid = threadIdx.x;
    const int wave = tid >> 6, lane = tid & 63;
    const int quad = lane >> 4, l15 = lane & 15;
    const int phase = blockIdx.x & 7;              // k-phase stagger

    __shared__ __align__(16) float xs[2][2048];    // 2 x 8 KB slots

    f32x4 acc[3] = {};

    // x DMA granule decode (granules g0 = tid, g1 = tid + 256):
    // half=tid&1, row=(tid>>1)&15, quad=(tid>>5)&3, ss = (tid>>7) + 2*granule
    const char* xg = (const char*)x
        + (size_t)(m0 + ((tid >> 1) & 15)) * 4096
        + (size_t)((tid >> 7) & 1) * 128 + (size_t)((tid >> 5) & 3) * 32
        + (size_t)(tid & 1) * 16;
    char* xl = (char*)&xs[0][0] + (size_t)tid * 16;

    // W fragment base pointers for this wave's 3 ntiles
    const bf16* wpb[3];
    #pragma unroll
    for (int i = 0; i < 3; ++i) {
        const int n = (wave * 3 + i) * 16 + l15;
        wpb[i] = wt + (size_t)(n >> 6) * WT_SZ + (size_t)(n & 63) * WT_STR;
    }

    // prologue: stage step 0 into slot 0 (granule 1: +256B global, +4096B LDS)
    {
        const size_t kb = (size_t)phase * 512;     // bytes along k
        dma16(xg + kb, xl);
        dma16(xg + kb + 256, xl + 4096);
    }

    for (int s = 0; s < 8; ++s) {
        const int slot = s & 1;
        __syncthreads();                           // drains slot's DMA; prior reads done
        if (s + 1 < 8) {
            const size_t kb = (size_t)(((s + 1) + phase) & 7) * 512;
            char* nxt = (char*)&xs[slot ^ 1][0] + (size_t)tid * 16;
            dma16(xg + kb, nxt);
            dma16(xg + kb + 256, nxt + 4096);
        }
        const int se = (s + phase) & 7;

        #pragma unroll
        for (int ss = 0; ss < 4; ++ss) {
            bf16x8 a;
            {
                const float* ap = &xs[slot][((ss * 4 + quad) * 16 + l15) * 8];
                const f32x4 lo = *(const f32x4*)ap;
                const f32x4 hi = *(const f32x4*)(ap + 4);
                a[0] = (bf16)lo[0]; a[1] = (bf16)lo[1];
                a[2] = (bf16)lo[2]; a[3] = (bf16)lo[3];
                a[4] = (bf16)hi[0]; a[5] = (bf16)hi[1];
                a[6] = (bf16)hi[2]; a[7] = (bf16)hi[3];
            }
            const int k = se * 128 + ss * 32 + quad * 8;
            #pragma unroll
            for (int i = 0; i < 3; ++i) {
                const bf16x8 wf = *(const bf16x8*)(wpb[i] + k);
                acc[i] = MFMA16(a, wf, acc[i]);
            }
        }
    }

    // epilogue: row t = m0+quad*4+r, col n = (wave*3+i)*16+l15
    #pragma unroll
    for (int i = 0; i < 3; ++i) {
        const int n = (wave * 3 + i) * 16 + l15;
        const int which = n >> 6, col = n & 63;
        #pragma unroll
        for (int r = 0; r < 4; ++r) {
            const int t = m0 + quad * 4 + r;
            const bf16 v = (bf16)acc[i][r];
            if (which == 0) {
                qw[(size_t)t * H_SZ + col] = v;
            } else if (which == 1) {
                // K slab: jt*4096 + ((col>>5)*4 + ((col>>3)&3))*512 + (t&63)*8 + (col&7)
                kw2[(size_t)(t >> 6) * 4096
                    + (size_t)(((col >> 5) << 2) + ((col >> 3) & 3)) * 512
                    + (size_t)(t & 63) * 8 + (col & 7)] = v;
            } else {
                // V slab: jt*4096 + ((((t>>5)&1)<<2) + ((t>>3)&3))*512 + col*8 + (t&7)
                vtw2[(size_t)(t >> 6) * 4096
                     + (size_t)((((t >> 5) & 1) << 2) + ((t >> 3) & 3)) * 512
                     + (size_t)col * 8 + (t & 7)] = v;
            }
        }
    }
}

// -------------------------------------------------------------------------
// K2: causal flash. grid 1024 x 256 (4 waves). Item (b, qt64, h): 64 q-rows,
// waves = 16-row groups sharing each KV slab. KV double-buffered: DMA for
// round r+1 issues before compute of round r (single barrier per round).
// Additive partials (no softmax max; exp2 domain) to pbuf.
// -------------------------------------------------------------------------
__global__ __launch_bounds__(256) void flash_attn(
    const bf16* __restrict__ qw, const bf16* __restrict__ kw2,
    const bf16* __restrict__ vtw2, float* __restrict__ pbuf)
{
    const int bx = blockIdx.x;
    const int item = (bx & 1) ? (1023 - (bx >> 1)) : (bx >> 1);
    const int qt = 63 - (item >> 4);
    const int b  = (item >> 2) & 3;
    const int h  = item & 3;
    const int i0 = qt * 64;
    const int nkv = qt + 1;

    const int tid = threadIdx.x;
    const int mg = tid >> 6, lane = tid & 63;
    const int quad = lane >> 4, l15 = lane & 15;

    __shared__ __align__(16) bf16 kvs[2][8192];     // 2 x 16 KB slots {K 8K | V 8K}
    __shared__ __align__(16) bf16 pls[4][16 * 72];  // 9.2 KB

    bf16x8 aq0, aq1;
    {
        const bf16* qp = qw + ((size_t)b * T_SZ + i0 + mg * 16 + l15) * H_SZ + quad * 8;
        aq0 = *(const bf16x8*)qp;
        aq1 = *(const bf16x8*)(qp + 32);
    }
    const bf16 onev = (bf16)1.0f;
    const bf16x8 vone = {onev, onev, onev, onev, onev, onev, onev, onev};

    const char* kgb = (const char*)kw2 + (size_t)b * 524288;
    const char* vgb = (const char*)vtw2 + (size_t)b * 524288;
    bf16* pl = pls[mg];

    f32x4 o[4] = {};
    f32x4 osum = {};

    auto dmaKV = [&](int jt, int slot) {
        const char* ks = kgb + (size_t)jt * 8192;
        const char* vs = vgb + (size_t)jt * 8192;
        char* dst = (char*)&kvs[slot][0] + (size_t)tid * 16;
        dma16(ks + (size_t)tid * 16, dst);
        dma16(ks + 4096 + (size_t)tid * 16, dst + 4096);
        dma16(vs + (size_t)tid * 16, dst + 8192);
        dma16(vs + 4096 + (size_t)tid * 16, dst + 12288);
    };

    if (h < nkv) dmaKV(h, 0);
    int slot = 0;
    for (int jt = h; jt < nkv; jt += 4, slot ^= 1) {
        __syncthreads();                            // drains slot DMA; old reads done
        if (jt + 4 < nkv) dmaKV(jt + 4, slot ^ 1);

        const bf16* kb = &kvs[slot][0];
        const bf16* vb = kb + 4096;

        f32x4 s4[4] = {};
        #pragma unroll
        for (int ct = 0; ct < 4; ++ct) {
            const bf16x8 k0 = *(const bf16x8*)(kb + (0 * 4 + quad) * 512 + (ct * 16 + l15) * 8);
            const bf16x8 k1 = *(const bf16x8*)(kb + (1 * 4 + quad) * 512 + (ct * 16 + l15) * 8);
            s4[ct] = MFMA16(aq0, k0, s4[ct]);
            s4[ct] = MFMA16(aq1, k1, s4[ct]);
        }
        if (jt == qt) {                             // diagonal tile: mask col > row
            #pragma unroll
            for (int ct = 0; ct < 4; ++ct) {
                const int col = ct * 16 + l15;
                const int row = mg * 16 + quad * 4;
                #pragma unroll
                for (int rr = 0; rr < 4; ++rr)
                    if (col > row + rr) s4[ct][rr] = -3.0e38f;
            }
        }
        #pragma unroll
        for (int ct = 0; ct < 4; ++ct)
            #pragma unroll
            for (int rr = 0; rr < 4; ++rr)
                pl[(quad * 4 + rr) * 72 + ct * 16 + l15] = (bf16)EXP2(s4[ct][rr]);
        const bf16x8 pa0 = *(const bf16x8*)&pl[l15 * 72 + quad * 8];
        const bf16x8 pa1 = *(const bf16x8*)&pl[l15 * 72 + 32 + quad * 8];

        #pragma unroll
        for (int ht = 0; ht < 4; ++ht) {
            const bf16x8 v0 = *(const bf16x8*)(vb + (0 * 4 + quad) * 512 + (ht * 16 + l15) * 8);
            const bf16x8 v1 = *(const bf16x8*)(vb + (1 * 4 + quad) * 512 + (ht * 16 + l15) * 8);
            o[ht] = MFMA16(pa0, v0, o[ht]);
            o[ht] = MFMA16(pa1, v1, o[ht]);
        }
        osum = MFMA16(pa0, vone, osum);
        osum = MFMA16(pa1, vone, osum);
    }

    float* pb = pbuf + (size_t)(((b * 64 + qt) * 4) + h) * P_STR;
    #pragma unroll
    for (int ht = 0; ht < 4; ++ht)
        #pragma unroll
        for (int rr = 0; rr < 4; ++rr)
            pb[(mg * 16 + quad * 4 + rr) * 64 + ht * 16 + l15] = o[ht][rr];
    if (l15 == 0) {
        #pragma unroll
        for (int rr = 0; rr < 4; ++rr)
            pb[4096 + mg * 16 + quad * 4 + rr] = osum[rr];
    }
}

// -------------------------------------------------------------------------
// K3: combine (unchanged). grid 256 x 256. out = sum_h O_h / sum_h l_h.
// -------------------------------------------------------------------------
__global__ __launch_bounds__(256) void combine(
    const float* __restrict__ pbuf, float* __restrict__ out)
{
    const int bq = blockIdx.x, tid = threadIdx.x;
    const int row = tid >> 2, c0 = (tid & 3) * 16;
    const float* p = pbuf + (size_t)bq * 4 * P_STR;

    f32x4 a0 = {}, a1 = {}, a2 = {}, a3 = {};
    float l = 0.f;
    #pragma unroll
    for (int h = 0; h < 4; ++h) {
        const float* ph = p + (size_t)h * P_STR + row * 64 + c0;
        a0 += *(const f32x4*)(ph);
        a1 += *(const f32x4*)(ph + 4);
        a2 += *(const f32x4*)(ph + 8);
        a3 += *(const f32x4*)(ph + 12);
        l  += p[(size_t)h * P_STR + 4096 + row];
    }
    const float inv = 1.0f / l;
    float* op = out + ((size_t)bq * 64 + row) * 64 + c0;
    *(f32x4*)(op)      = a0 * inv;
    *(f32x4*)(op + 4)  = a1 * inv;
    *(f32x4*)(op + 8)  = a2 * inv;
    *(f32x4*)(op + 12) = a3 * inv;
}

extern "C" void kernel_launch(void* const* d_in, const int* in_sizes, int n_in,
                              void* d_out, int out_size, void* d_ws, size_t ws_size,
                              hipStream_t stream) {
    const float* x  = (const float*)d_in[0];
    const float* Wq = (const float*)d_in[1];
    const float* Wk = (const float*)d_in[2];
    const float* Wv = (const float*)d_in[3];

    bf16* qw   = (bf16*)d_ws;                          // 2 MB, plain [t][h]
    bf16* kw2  = qw + (size_t)M_SZ * H_SZ;             // 2 MB, per-kv-tile slabs
    bf16* vtw2 = kw2 + (size_t)M_SZ * H_SZ;            // 2 MB, per-kv-tile slabs
    bf16* wt   = vtw2 + (size_t)M_SZ * H_SZ;           // 408 KB, [which][n][k] str 1088
    float* pbuf = (float*)(wt + 3 * WT_SZ);            // 17 MB partials
    float* out = (float*)d_out;

    wt_prep<<<48, 256, 0, stream>>>(Wq, Wk, Wv, wt);
    qkv_proj<<<M_SZ / 16, 256, 0, stream>>>(x, wt, qw, kw2, vtw2);
    flash_attn<<<1024, 256, 0, stream>>>(qw, kw2, vtw2, pbuf);
    combine<<<256, 256, 0, stream>>>(pbuf, out);
}